// Round 15
// baseline (243.818 us; speedup 1.0000x reference)
//
#include <hip/hip_runtime.h>
#include <hip/hip_bf16.h>

// out[q,c] = sum_n exp(-50*r2(q,n)) * d_val[n,c] / (1e-4 + sum_n exp(-50*r2(q,n)))
// Q=16384, N=8192, C=64, f32. sigma=0.1 => pairs with r>=1.0 contribute
// w <= 2^-72 (output error <= ~1e-13) -> cell-list culling with h=1.0:
// bin points+queries into a 9^3 grid, each 16-query group (one cell) scans
// only its 27 neighbor cells' points (~12x work reduction). Inner step body
// is the proven dense MFMA step (TILES=1) with range masking. Direct output
// write (each query in exactly one group) -- no partials, no reduce pass.

#define QTOT 16384
#define NTOT 8192
#define CCH  64
#define GDIM 9
#define NCELL 729                 // 9^3
#define XMINF -4.5f
#define PADN 32
#define NSLOT (NTOT + PADN)       // 8224
#define MAXE 1760                 // >= max table entries (<=1707)

typedef __attribute__((ext_vector_type(8))) short bf16x8;
typedef __attribute__((ext_vector_type(4))) float f32x4;
typedef __attribute__((ext_vector_type(4))) int   i32x4;

// exp(-50 r^2) = exp2( q . p' + A_q + B_n ), p' = 144.2695*p, B_n = -72.13474*|p|^2
#define K2F 144.269504089f
#define K1F 72.1347520444f

__device__ __forceinline__ int cell_of(float x, float y, float z) {
    int cx = (int)floorf(x - XMINF); cx = cx < 0 ? 0 : (cx > 8 ? 8 : cx);
    int cy = (int)floorf(y - XMINF); cy = cy < 0 ? 0 : (cy > 8 ? 8 : cy);
    int cz = (int)floorf(z - XMINF); cz = cz < 0 ? 0 : (cz > 8 ? 8 : cz);
    return (cz * GDIM + cy) * GDIM + cx;
}

// ---- K0: zero counters, init pad slots ----
__global__ __launch_bounds__(256)
void k_init(int* cnt4, float4* sp4, __hip_bfloat16* svt) {
    int i = blockIdx.x * 256 + threadIdx.x;
    if (i < 4 * NCELL) cnt4[i] = 0;                       // cntP,fillP,cntQ,fillQ
    if (i < PADN) sp4[NTOT + i] = make_float4(0.f, 0.f, 0.f, -3.0e38f);
    if (i < CCH * PADN) {
        int c = i >> 5, j = i & 31;
        svt[(size_t)c * NSLOT + NTOT + j] = __float2bfloat16(0.f);
    }
}

// ---- K1/K2: bin points / queries ----
__global__ __launch_bounds__(256)
void k_binp(const float* __restrict__ dp, int* __restrict__ cellP, int* __restrict__ cntP) {
    int n = blockIdx.x * 256 + threadIdx.x; if (n >= NTOT) return;
    int c = cell_of(dp[3 * n], dp[3 * n + 1], dp[3 * n + 2]);
    cellP[n] = c; atomicAdd(&cntP[c], 1);
}
__global__ __launch_bounds__(256)
void k_binq(const float* __restrict__ qp, int* __restrict__ cellQ, int* __restrict__ cntQ) {
    int q = blockIdx.x * 256 + threadIdx.x; if (q >= QTOT) return;
    int c = cell_of(qp[3 * q], qp[3 * q + 1], qp[3 * q + 2]);
    cellQ[q] = c; atomicAdd(&cntQ[c], 1);
}

// ---- K3: single-block scans (offsP, offsQ) + query-group table ----
__global__ __launch_bounds__(1024)
void k_scan(const int* __restrict__ cntP, const int* __restrict__ cntQ,
            int* __restrict__ offsP, int* __restrict__ offsQ,
            int* __restrict__ tblCell, int* __restrict__ tblStart,
            int* __restrict__ tblCnt, int* __restrict__ nent) {
    __shared__ int s[1024];
    const int i = threadIdx.x;
    int v = (i < NCELL) ? cntP[i] : 0;
    s[i] = v; __syncthreads();
    for (int off = 1; off < 1024; off <<= 1) {
        int add = (i >= off) ? s[i - off] : 0;
        __syncthreads(); s[i] += add; __syncthreads();
    }
    if (i < NCELL) offsP[i] = s[i] - v;
    if (i == NCELL - 1) offsP[NCELL] = s[i];
    __syncthreads();

    int vq = (i < NCELL) ? cntQ[i] : 0;
    s[i] = vq; __syncthreads();
    for (int off = 1; off < 1024; off <<= 1) {
        int add = (i >= off) ? s[i - off] : 0;
        __syncthreads(); s[i] += add; __syncthreads();
    }
    int myQoff = s[i] - vq;
    if (i < NCELL) offsQ[i] = myQoff;
    if (i == NCELL - 1) offsQ[NCELL] = s[i];
    __syncthreads();

    int g = (i < NCELL) ? ((vq + 15) >> 4) : 0;
    s[i] = g; __syncthreads();
    for (int off = 1; off < 1024; off <<= 1) {
        int add = (i >= off) ? s[i - off] : 0;
        __syncthreads(); s[i] += add; __syncthreads();
    }
    int goff = s[i] - g;
    if (i == NCELL - 1) nent[0] = s[i];
    if (i < NCELL) {
        for (int k = 0; k < g; ++k) {
            tblCell[goff + k]  = i;
            tblStart[goff + k] = myQoff + k * 16;
            int rem = vq - k * 16;
            tblCnt[goff + k]   = rem < 16 ? rem : 16;
        }
    }
}

// ---- K4: scatter points -> sorted P4 ----
__global__ __launch_bounds__(256)
void k_scatp(const float* __restrict__ dp, const int* __restrict__ cellP,
             const int* __restrict__ offsP, int* __restrict__ fillP,
             int* __restrict__ permP, float4* __restrict__ sp4) {
    int n = blockIdx.x * 256 + threadIdx.x; if (n >= NTOT) return;
    int c = cellP[n];
    int slot = offsP[c] + atomicAdd(&fillP[c], 1);
    permP[slot] = n;
    float px = dp[3 * n], py = dp[3 * n + 1], pz = dp[3 * n + 2];
    sp4[slot] = make_float4(K2F * px, K2F * py, K2F * pz,
                            -K1F * (px * px + py * py + pz * pz));
}

// ---- K5: scatter queries (perm only) ----
__global__ __launch_bounds__(256)
void k_scatq(const int* __restrict__ cellQ, const int* __restrict__ offsQ,
             int* __restrict__ fillQ, int* __restrict__ permQ) {
    int q = blockIdx.x * 256 + threadIdx.x; if (q >= QTOT) return;
    int c = cellQ[q];
    int slot = offsQ[c] + atomicAdd(&fillQ[c], 1);
    permQ[slot] = q;
}

// ---- K6: gather+transpose V -> bf16 [c][slot] ----
__global__ __launch_bounds__(256)
void k_transv(const float* __restrict__ dv, const int* __restrict__ permP,
              __hip_bfloat16* __restrict__ svt) {
    int tid = threadIdx.x;
    int cgrp = tid >> 6, j = tid & 63;
    int slot = blockIdx.x * 64 + j;
    int orig = permP[slot];
    const float* row = dv + (size_t)orig * CCH;
#pragma unroll
    for (int cc = 0; cc < 16; ++cc) {
        int c = cgrp * 16 + cc;
        svt[(size_t)c * NSLOT + slot] = __float2bfloat16(row[c]);
    }
}

// ---- K7: main. wave = one 16-query group; 27-neighbor-cell point scan ----
__global__ __launch_bounds__(256)
void splat_cell(const float* __restrict__ q_pos,
                const float4* __restrict__ sp4,
                const __hip_bfloat16* __restrict__ svt,
                const int* __restrict__ permQ,
                const int* __restrict__ offsP,
                const int* __restrict__ tblCell,
                const int* __restrict__ tblStart,
                const int* __restrict__ tblCnt,
                const int* __restrict__ nent,
                float* __restrict__ out)
{
    const int wave = threadIdx.x >> 6;
    const int lane = threadIdx.x & 63;
    const int r  = lane & 15;     // A row (query within group) / C col (channel)
    const int hi = lane >> 4;     // k-group
    const int e = blockIdx.x * 4 + wave;
    if (e >= nent[0]) return;
    const int cell = tblCell[e], qstart = tblStart[e], qcnt = tblCnt[e];

    const int sq = qstart + (r < qcnt ? r : qcnt - 1);   // clamp pad lanes
    const int qo = permQ[sq];
    const float qx = q_pos[3 * qo], qy = q_pos[3 * qo + 1], qz = q_pos[3 * qo + 2];
    const float Aq = -K1F * (qx * qx + qy * qy + qz * qz);

    f32x4 acc[4];
#pragma unroll
    for (int cg = 0; cg < 4; ++cg) acc[cg] = (f32x4)(0.0f);
    float wsum = 0.0f;

    const int cz = cell / 81, rem0 = cell % 81, cy = rem0 / 9, cx = rem0 % 9;
    for (int dz = -1; dz <= 1; ++dz) {
        const int z2 = cz + dz; if ((unsigned)z2 > 8u) continue;
        for (int dy = -1; dy <= 1; ++dy) {
            const int y2 = cy + dy; if ((unsigned)y2 > 8u) continue;
            for (int dx = -1; dx <= 1; ++dx) {
                const int x2 = cx + dx; if ((unsigned)x2 > 8u) continue;
                const int nc = (z2 * 9 + y2) * 9 + x2;
                const int nb0 = offsP[nc], nend2 = offsP[nc + 1];
                for (int nb = nb0; nb < nend2; nb += 32) {
                    // proven dense step body (TILES=1) + range masking
                    float4 p4[8];
                    const float4* pp = sp4 + nb + 8 * hi;
#pragma unroll
                    for (int b = 0; b < 8; ++b) p4[b] = pp[b];
#pragma unroll
                    for (int b = 0; b < 8; ++b)
                        if (nb + 8 * hi + b >= nend2) p4[b].w = -3.0e38f;  // w -> 0

                    union BF { i32x4 i; bf16x8 v; } bfr[4];
#pragma unroll
                    for (int cg = 0; cg < 4; ++cg)
                        bfr[cg].i = *(const i32x4*)(svt + (size_t)(cg * 16 + r) * NSLOT + nb + 8 * hi);

                    union AF { unsigned u[4]; bf16x8 v; } af;
                    float w[8];
#pragma unroll
                    for (int b = 0; b < 8; ++b) {
                        float bias = p4[b].w + Aq;
                        float arg = fmaf(qz, p4[b].z, fmaf(qy, p4[b].y, fmaf(qx, p4[b].x, bias)));
                        w[b] = __builtin_amdgcn_exp2f(arg);
                        wsum += w[b];
                    }
#pragma unroll
                    for (int d = 0; d < 4; ++d) {
                        unsigned u;
                        asm("v_cvt_pk_bf16_f32 %0, %1, %2" : "=v"(u) : "v"(w[2 * d]), "v"(w[2 * d + 1]));
                        af.u[d] = u;
                    }
#pragma unroll
                    for (int cg = 0; cg < 4; ++cg)
                        acc[cg] = __builtin_amdgcn_mfma_f32_16x16x32_bf16(af.v, bfr[cg].v, acc[cg], 0, 0, 0);
                }
            }
        }
    }

    // full wsum per query row r (reduce over hi k-groups)
    float wsumF = wsum;
    wsumF += __shfl_xor(wsumF, 16);
    wsumF += __shfl_xor(wsumF, 32);

    // C layout: col = r (channel), row = 4*hi + j (query within group)
#pragma unroll
    for (int j = 0; j < 4; ++j) {
        const int qrow = 4 * hi + j;
        const float wsr = __shfl(wsumF, qrow);   // lane qrow holds row qrow's wsum
        if (qrow < qcnt) {
            const int qorig = permQ[qstart + qrow];
            const float inv = 1.0f / (1e-4f + wsr);
            float* orow = out + (size_t)qorig * CCH;
#pragma unroll
            for (int cg = 0; cg < 4; ++cg)
                orow[cg * 16 + r] = acc[cg][j] * inv;
        }
    }
}

// ---------- fallback: single pass VALU ----------
__global__ __launch_bounds__(256)
void splat_direct(const float* __restrict__ q_pos,
                  const float* __restrict__ d_pos,
                  const float* __restrict__ d_val,
                  float* __restrict__ out, int Q, int N)
{
    const int q = blockIdx.x * blockDim.x + threadIdx.x;
    const float qx = q_pos[q * 3 + 0], qy = q_pos[q * 3 + 1], qz = q_pos[q * 3 + 2];
    float acc[CCH];
#pragma unroll
    for (int c = 0; c < CCH; ++c) acc[c] = 0.0f;
    float wsum = 0.0f;
    for (int n = 0; n < N; ++n) {
        float dx = qx - d_pos[n * 3 + 0];
        float dy = qy - d_pos[n * 3 + 1];
        float dz = qz - d_pos[n * 3 + 2];
        float r2 = fmaf(dx, dx, fmaf(dy, dy, dz * dz));
        float w = __expf(-50.0f * r2);
        wsum += w;
        const float4* row4 = reinterpret_cast<const float4*>(d_val + (size_t)n * CCH);
#pragma unroll
        for (int j = 0; j < CCH / 4; ++j) {
            float4 v = row4[j];
            acc[4 * j + 0] = fmaf(w, v.x, acc[4 * j + 0]);
            acc[4 * j + 1] = fmaf(w, v.y, acc[4 * j + 1]);
            acc[4 * j + 2] = fmaf(w, v.z, acc[4 * j + 2]);
            acc[4 * j + 3] = fmaf(w, v.w, acc[4 * j + 3]);
        }
    }
    float inv = 1.0f / (1e-4f + wsum);
#pragma unroll
    for (int c = 0; c < CCH; ++c) out[(size_t)q * CCH + c] = acc[c] * inv;
}

extern "C" void kernel_launch(void* const* d_in, const int* in_sizes, int n_in,
                              void* d_out, int out_size, void* d_ws, size_t ws_size,
                              hipStream_t stream) {
    const float* q_pos = (const float*)d_in[0];
    const float* d_pos = (const float*)d_in[1];
    const float* d_val = (const float*)d_in[2];
    float* out = (float*)d_out;

    // workspace layout (bytes)
    const size_t off_sp4 = 0;                                  // NSLOT float4
    const size_t off_svt = (size_t)NSLOT * 16;                 // 131584
    const size_t off_int = off_svt + (size_t)CCH * NSLOT * 2;  // 1184256
    const size_t n_ints  = 4 * NCELL + 2 * (NCELL + 1) + 1 + 3 * MAXE
                         + NTOT + QTOT + NTOT + QTOT;
    const size_t NEED = off_int + n_ints * 4;

    if (ws_size < NEED) {
        splat_direct<<<dim3(QTOT / 256), dim3(256), 0, stream>>>(
            q_pos, d_pos, d_val, out, QTOT, NTOT);
        return;
    }

    float4*         sp4 = (float4*)((char*)d_ws + off_sp4);
    __hip_bfloat16* svt = (__hip_bfloat16*)((char*)d_ws + off_svt);
    int* I = (int*)((char*)d_ws + off_int);
    int* cntP   = I;                 // 729
    int* fillP  = I + 729;
    int* cntQ   = I + 1458;
    int* fillQ  = I + 2187;
    int* offsP  = I + 2916;          // 730
    int* offsQ  = I + 3646;          // 730
    int* nent   = I + 4376;          // 1
    int* tblCell  = I + 4377;        // MAXE
    int* tblStart = I + 4377 + MAXE;
    int* tblCnt   = I + 4377 + 2 * MAXE;
    int* cellP  = I + 4377 + 3 * MAXE;            // 8192
    int* cellQ  = cellP + NTOT;                   // 16384
    int* permP  = cellQ + QTOT;                   // 8192
    int* permQ  = permP + NTOT;                   // 16384

    k_init <<<dim3(12),  dim3(256), 0, stream>>>(cntP, sp4, svt);
    k_binp <<<dim3(32),  dim3(256), 0, stream>>>(d_pos, cellP, cntP);
    k_binq <<<dim3(64),  dim3(256), 0, stream>>>(q_pos, cellQ, cntQ);
    k_scan <<<dim3(1),   dim3(1024), 0, stream>>>(cntP, cntQ, offsP, offsQ,
                                                  tblCell, tblStart, tblCnt, nent);
    k_scatp<<<dim3(32),  dim3(256), 0, stream>>>(d_pos, cellP, offsP, fillP, permP, sp4);
    k_scatq<<<dim3(64),  dim3(256), 0, stream>>>(cellQ, offsQ, fillQ, permQ);
    k_transv<<<dim3(NTOT / 64), dim3(256), 0, stream>>>(d_val, permP, svt);
    splat_cell<<<dim3(MAXE / 4), dim3(256), 0, stream>>>(
        q_pos, sp4, svt, permQ, offsP, tblCell, tblStart, tblCnt, nent, out);
}

// Round 16
// 71.473 us; speedup vs baseline: 3.4113x; 3.4113x over previous
//
#include <hip/hip_runtime.h>
#include <hip/hip_bf16.h>

// out[q,c] = sum_n exp(-50*r2(q,n)) * d_val[n,c] / (1e-4 + sum_n exp(-50*r2(q,n)))
// Q=16384, N=8192, C=64, f32 in/out.
// MFMA formulation: W (generated bf16) @ V (bf16), f32 accumulate.
// Round 16: R14 body + wsum computed via ones-column MFMA (acc_w[t] =
// mfma(af[t], ones, acc_w[t])) on the idle matrix pipe instead of 32 VALU
// adds/step + shfl reduce. Additive change only -- NO reordering of the
// load schedule (R3/R5/R6/R7/R13 all garbled on memory-schedule rewrites).

#define QTOT 16384
#define NTOT 8192
#define CCH  64

typedef __attribute__((ext_vector_type(8))) short bf16x8;
typedef __attribute__((ext_vector_type(4))) float f32x4;
typedef __attribute__((ext_vector_type(4))) int   i32x4;

// exp(-50 r^2) = exp2( q . p' + A_q + B_n ), p' = 144.2695*p, B_n = -72.13474*|p|^2
#define K2F 144.269504089f
#define K1F 72.1347520444f

// ---------- prep: P4[n] = {K2*px, K2*py, K2*pz, -K1*|p|^2} ----------
__global__ __launch_bounds__(256)
void prep_p4(const float* __restrict__ dp, float4* __restrict__ P4) {
    int n = blockIdx.x * 256 + threadIdx.x;
    if (n >= NTOT) return;
    float px = dp[3 * n + 0], py = dp[3 * n + 1], pz = dp[3 * n + 2];
    float4 r;
    r.x = K2F * px; r.y = K2F * py; r.z = K2F * pz;
    r.w = -K1F * (px * px + py * py + pz * pz);
    P4[n] = r;
}

// ---------- prep: Vt[c][n] = bf16(d_val[n][c]) (transposed, bf16) ----------
__global__ __launch_bounds__(256)
void prep_vt(const float* __restrict__ dv, __hip_bfloat16* __restrict__ Vt) {
    int t = blockIdx.x * 256 + threadIdx.x;   // t = c*NTOT + n
    int c = t >> 13;                          // NTOT = 8192
    int n = t & (NTOT - 1);
    Vt[t] = __float2bfloat16(dv[n * CCH + c]);
}

// ---------- main: 4 waves/block; 64 q x 64 c per wave; n-slice in steps of 32 ----------
__global__ __launch_bounds__(256)
void splat_mfma(const float* __restrict__ q_pos,
                const float4* __restrict__ P4,
                const __hip_bfloat16* __restrict__ Vt,   // [64][NTOT]
                float* __restrict__ ws_val,              // [NS][QTOT][64]
                float* __restrict__ ws_w,                // [NS][QTOT]
                int npers)                               // n per slice (mult of 32)
{
    const int wave = threadIdx.x >> 6;
    const int lane = threadIdx.x & 63;
    const int r    = lane & 15;     // A row / B col / C col index
    const int hi   = lane >> 4;     // k-group
    const int qbase = blockIdx.x * 256 + wave * 64;
    const int s  = blockIdx.y;
    const int n0 = s * npers;

    float qx[4], qy[4], qz[4], Aq[4];
#pragma unroll
    for (int t = 0; t < 4; ++t) {
        int q = qbase + t * 16 + r;
        float x = q_pos[3 * q + 0], y = q_pos[3 * q + 1], z = q_pos[3 * q + 2];
        qx[t] = x; qy[t] = y; qz[t] = z;
        Aq[t] = -K1F * (x * x + y * y + z * z);
    }

    f32x4 acc[4][4];
#pragma unroll
    for (int t = 0; t < 4; ++t)
#pragma unroll
        for (int cg = 0; cg < 4; ++cg)
            acc[t][cg] = (f32x4)(0.0f);

    // wsum accumulators (ones-column MFMA): every C column holds wsum[row]
    f32x4 acc_w[4];
#pragma unroll
    for (int t = 0; t < 4; ++t) acc_w[t] = (f32x4)(0.0f);

    // constant all-ones bf16 B fragment (1.0 = 0x3F80)
    union ONES { short s[8]; bf16x8 v; } ones;
#pragma unroll
    for (int i = 0; i < 8; ++i) ones.s[i] = (short)0x3F80;

    for (int nb = n0; nb < n0 + npers; nb += 32) {
        // P4 for this lane's 8 n values (16 lanes per hi-group share -> broadcast)
        float4 p4[8];
        const float4* pp = P4 + nb + 8 * hi;
#pragma unroll
        for (int b = 0; b < 8; ++b) p4[b] = pp[b];

        // B fragments: lane holds V[nb+8*hi+b][cg*16+r] = Vt[cg*16+r][nb+8*hi+b]
        union BF { i32x4 i; bf16x8 v; } bfr[4];
#pragma unroll
        for (int cg = 0; cg < 4; ++cg) {
            const i32x4* bp = (const i32x4*)(Vt + (size_t)(cg * 16 + r) * NTOT + nb + 8 * hi);
            bfr[cg].i = *bp;
        }

        // A fragments: lane holds W[qbase+t*16+r][k=8*hi+b]
        union AF { unsigned u[4]; bf16x8 v; } af[4];
#pragma unroll
        for (int t = 0; t < 4; ++t) {
            float w[8];
#pragma unroll
            for (int b = 0; b < 8; ++b) {
                float bias = p4[b].w + Aq[t];
                float arg = fmaf(qz[t], p4[b].z, fmaf(qy[t], p4[b].y, fmaf(qx[t], p4[b].x, bias)));
                w[b] = __builtin_amdgcn_exp2f(arg);
            }
#pragma unroll
            for (int d = 0; d < 4; ++d) {
                unsigned u;
                asm("v_cvt_pk_bf16_f32 %0, %1, %2" : "=v"(u) : "v"(w[2 * d]), "v"(w[2 * d + 1]));
                af[t].u[d] = u;
            }
        }

#pragma unroll
        for (int t = 0; t < 4; ++t)
#pragma unroll
            for (int cg = 0; cg < 4; ++cg)
                acc[t][cg] = __builtin_amdgcn_mfma_f32_16x16x32_bf16(af[t].v, bfr[cg].v, acc[t][cg], 0, 0, 0);

#pragma unroll
        for (int t = 0; t < 4; ++t)
            acc_w[t] = __builtin_amdgcn_mfma_f32_16x16x32_bf16(af[t].v, ones.v, acc_w[t], 0, 0, 0);
    }

    // C layout: col = lane&15 (channel), row = 4*hi + j (q offset)
    float* wsv = ws_val + (size_t)s * QTOT * CCH;
#pragma unroll
    for (int t = 0; t < 4; ++t) {
#pragma unroll
        for (int cg = 0; cg < 4; ++cg)
#pragma unroll
            for (int j = 0; j < 4; ++j) {
                int q = qbase + t * 16 + 4 * hi + j;
                int c = cg * 16 + r;
                wsv[(size_t)q * CCH + c] = acc[t][cg][j];
            }
        // acc_w: every column r holds wsum of row 4*hi+j; write from r==0
        if (r == 0) {
#pragma unroll
            for (int j = 0; j < 4; ++j)
                ws_w[(size_t)s * QTOT + qbase + t * 16 + 4 * hi + j] = acc_w[t][j];
        }
    }
}

// ---------- reduce + normalize (float4 vectorized) ----------
__global__ __launch_bounds__(256)
void splat_reduce4(const float4* __restrict__ ws_val,   // [NS][QTOT*16] float4
                   const float* __restrict__ ws_w,
                   float4* __restrict__ out, int NS) {
    int t = blockIdx.x * 256 + threadIdx.x;   // float4 index: q*16 + c4
    int q = t >> 4;
    float4 v = make_float4(0.f, 0.f, 0.f, 0.f);
    float wsum = 0.0f;
    for (int s = 0; s < NS; ++s) {
        float4 a = ws_val[(size_t)s * (QTOT * 16) + t];
        v.x += a.x; v.y += a.y; v.z += a.z; v.w += a.w;
        wsum += ws_w[(size_t)s * QTOT + q];
    }
    float inv = 1.0f / (1e-4f + wsum);
    v.x *= inv; v.y *= inv; v.z *= inv; v.w *= inv;
    out[t] = v;
}

// ---------- fallback: single pass VALU ----------
__global__ __launch_bounds__(256)
void splat_direct(const float* __restrict__ q_pos,
                  const float* __restrict__ d_pos,
                  const float* __restrict__ d_val,
                  float* __restrict__ out, int Q, int N)
{
    const int q = blockIdx.x * blockDim.x + threadIdx.x;
    const float qx = q_pos[q * 3 + 0], qy = q_pos[q * 3 + 1], qz = q_pos[q * 3 + 2];
    float acc[CCH];
#pragma unroll
    for (int c = 0; c < CCH; ++c) acc[c] = 0.0f;
    float wsum = 0.0f;
    for (int n = 0; n < N; ++n) {
        float dx = qx - d_pos[n * 3 + 0];
        float dy = qy - d_pos[n * 3 + 1];
        float dz = qz - d_pos[n * 3 + 2];
        float r2 = fmaf(dx, dx, fmaf(dy, dy, dz * dz));
        float w = __expf(-50.0f * r2);
        wsum += w;
        const float4* row4 = reinterpret_cast<const float4*>(d_val + (size_t)n * CCH);
#pragma unroll
        for (int j = 0; j < CCH / 4; ++j) {
            float4 v = row4[j];
            acc[4 * j + 0] = fmaf(w, v.x, acc[4 * j + 0]);
            acc[4 * j + 1] = fmaf(w, v.y, acc[4 * j + 1]);
            acc[4 * j + 2] = fmaf(w, v.z, acc[4 * j + 2]);
            acc[4 * j + 3] = fmaf(w, v.w, acc[4 * j + 3]);
        }
    }
    float inv = 1.0f / (1e-4f + wsum);
#pragma unroll
    for (int c = 0; c < CCH; ++c) out[(size_t)q * CCH + c] = acc[c] * inv;
}

extern "C" void kernel_launch(void* const* d_in, const int* in_sizes, int n_in,
                              void* d_out, int out_size, void* d_ws, size_t ws_size,
                              hipStream_t stream) {
    const float* q_pos = (const float*)d_in[0];
    const float* d_pos = (const float*)d_in[1];
    const float* d_val = (const float*)d_in[2];
    float* out = (float*)d_out;

    const size_t p4_bytes = (size_t)NTOT * 16;              // 128 KiB
    const size_t vt_bytes = (size_t)NTOT * CCH * 2;         // 1 MiB
    auto need = [&](int ns) {
        return p4_bytes + vt_bytes
             + (size_t)ns * QTOT * CCH * 4 + (size_t)ns * QTOT * 4;
    };

    int NS;
    if (need(8) <= ws_size)       NS = 8;    // 512 blocks = 2048 waves = reg-cap fill
    else if (need(4) <= ws_size)  NS = 4;
    else {
        splat_direct<<<dim3(QTOT / 256), dim3(256), 0, stream>>>(
            q_pos, d_pos, d_val, out, QTOT, NTOT);
        return;
    }

    float4*          P4 = (float4*)d_ws;
    __hip_bfloat16*  Vt = (__hip_bfloat16*)((char*)d_ws + p4_bytes);
    float*       ws_valp = (float*)((char*)d_ws + p4_bytes + vt_bytes);
    float*         ws_wp = ws_valp + (size_t)NS * QTOT * CCH;

    prep_p4<<<dim3(NTOT / 256), dim3(256), 0, stream>>>(d_pos, P4);
    prep_vt<<<dim3(NTOT * CCH / 256), dim3(256), 0, stream>>>(d_val, Vt);

    splat_mfma<<<dim3(QTOT / 256, NS), dim3(256), 0, stream>>>(
        q_pos, P4, Vt, ws_valp, ws_wp, NTOT / NS);

    splat_reduce4<<<dim3(QTOT * CCH / 4 / 256), dim3(256), 0, stream>>>(
        (const float4*)ws_valp, ws_wp, (float4*)out, NS);
}

// Round 17
// 70.137 us; speedup vs baseline: 3.4763x; 1.0190x over previous
//
#include <hip/hip_runtime.h>
#include <hip/hip_bf16.h>

// out[q,c] = sum_n exp(-50*r2(q,n)) * d_val[n,c] / (1e-4 + sum_n exp(-50*r2(q,n)))
// Q=16384, N=8192, C=64, f32 in/out.
// MFMA formulation: W (generated bf16) @ V (bf16), f32 accumulate.
// Round 17: R14 main-loop BYTE-IDENTICAL (VALU wsum, absmax 0.0156 base).
// Epilogue-only change: ws_val partials stored as bf16 (halves main-kernel
// write drain 33->16.6MB and reduce-pass read 33->16.8MB). ws_w stays f32.
// The inner loop's memory schedule is untouched (R3/5/6/7/13 lesson).

#define QTOT 16384
#define NTOT 8192
#define CCH  64

typedef __attribute__((ext_vector_type(8))) short bf16x8;
typedef __attribute__((ext_vector_type(4))) float f32x4;
typedef __attribute__((ext_vector_type(4))) int   i32x4;

// exp(-50 r^2) = exp2( q . p' + A_q + B_n ), p' = 144.2695*p, B_n = -72.13474*|p|^2
#define K2F 144.269504089f
#define K1F 72.1347520444f

// ---------- prep: P4[n] = {K2*px, K2*py, K2*pz, -K1*|p|^2} ----------
__global__ __launch_bounds__(256)
void prep_p4(const float* __restrict__ dp, float4* __restrict__ P4) {
    int n = blockIdx.x * 256 + threadIdx.x;
    if (n >= NTOT) return;
    float px = dp[3 * n + 0], py = dp[3 * n + 1], pz = dp[3 * n + 2];
    float4 r;
    r.x = K2F * px; r.y = K2F * py; r.z = K2F * pz;
    r.w = -K1F * (px * px + py * py + pz * pz);
    P4[n] = r;
}

// ---------- prep: Vt[c][n] = bf16(d_val[n][c]) (transposed, bf16) ----------
__global__ __launch_bounds__(256)
void prep_vt(const float* __restrict__ dv, __hip_bfloat16* __restrict__ Vt) {
    int t = blockIdx.x * 256 + threadIdx.x;   // t = c*NTOT + n
    int c = t >> 13;                          // NTOT = 8192
    int n = t & (NTOT - 1);
    Vt[t] = __float2bfloat16(dv[n * CCH + c]);
}

// ---------- main: 4 waves/block; 64 q x 64 c per wave; n-slice in steps of 32 ----------
__global__ __launch_bounds__(256)
void splat_mfma(const float* __restrict__ q_pos,
                const float4* __restrict__ P4,
                const __hip_bfloat16* __restrict__ Vt,   // [64][NTOT]
                __hip_bfloat16* __restrict__ ws_val,     // [NS][QTOT][64] bf16
                float* __restrict__ ws_w,                // [NS][QTOT]
                int npers)                               // n per slice (mult of 32)
{
    const int wave = threadIdx.x >> 6;
    const int lane = threadIdx.x & 63;
    const int r    = lane & 15;     // A row / B col / C col index
    const int hi   = lane >> 4;     // k-group
    const int qbase = blockIdx.x * 256 + wave * 64;
    const int s  = blockIdx.y;
    const int n0 = s * npers;

    float qx[4], qy[4], qz[4], Aq[4];
#pragma unroll
    for (int t = 0; t < 4; ++t) {
        int q = qbase + t * 16 + r;
        float x = q_pos[3 * q + 0], y = q_pos[3 * q + 1], z = q_pos[3 * q + 2];
        qx[t] = x; qy[t] = y; qz[t] = z;
        Aq[t] = -K1F * (x * x + y * y + z * z);
    }

    f32x4 acc[4][4];
#pragma unroll
    for (int t = 0; t < 4; ++t)
#pragma unroll
        for (int cg = 0; cg < 4; ++cg)
            acc[t][cg] = (f32x4)(0.0f);
    float wsum[4] = {0.0f, 0.0f, 0.0f, 0.0f};

    for (int nb = n0; nb < n0 + npers; nb += 32) {
        // P4 for this lane's 8 n values (16 lanes per hi-group share -> broadcast)
        float4 p4[8];
        const float4* pp = P4 + nb + 8 * hi;
#pragma unroll
        for (int b = 0; b < 8; ++b) p4[b] = pp[b];

        // B fragments: lane holds V[nb+8*hi+b][cg*16+r] = Vt[cg*16+r][nb+8*hi+b]
        union BF { i32x4 i; bf16x8 v; } bfr[4];
#pragma unroll
        for (int cg = 0; cg < 4; ++cg) {
            const i32x4* bp = (const i32x4*)(Vt + (size_t)(cg * 16 + r) * NTOT + nb + 8 * hi);
            bfr[cg].i = *bp;
        }

        // A fragments: lane holds W[qbase+t*16+r][k=8*hi+b]
        union AF { unsigned u[4]; bf16x8 v; } af[4];
#pragma unroll
        for (int t = 0; t < 4; ++t) {
            float w[8];
#pragma unroll
            for (int b = 0; b < 8; ++b) {
                float bias = p4[b].w + Aq[t];
                float arg = fmaf(qz[t], p4[b].z, fmaf(qy[t], p4[b].y, fmaf(qx[t], p4[b].x, bias)));
                w[b] = __builtin_amdgcn_exp2f(arg);
                wsum[t] += w[b];
            }
#pragma unroll
            for (int d = 0; d < 4; ++d) {
                unsigned u;
                asm("v_cvt_pk_bf16_f32 %0, %1, %2" : "=v"(u) : "v"(w[2 * d]), "v"(w[2 * d + 1]));
                af[t].u[d] = u;
            }
        }

#pragma unroll
        for (int t = 0; t < 4; ++t)
#pragma unroll
            for (int cg = 0; cg < 4; ++cg)
                acc[t][cg] = __builtin_amdgcn_mfma_f32_16x16x32_bf16(af[t].v, bfr[cg].v, acc[t][cg], 0, 0, 0);
    }

    // wsum: lanes with same r hold disjoint n-subsets of the same q -> reduce over hi
#pragma unroll
    for (int t = 0; t < 4; ++t) {
        float wv = wsum[t];
        wv += __shfl_xor(wv, 16);
        wv += __shfl_xor(wv, 32);
        wsum[t] = wv;
    }

    // C layout: col = lane&15 (channel), row = 4*hi + j (q offset); bf16 stores
    __hip_bfloat16* wsv = ws_val + (size_t)s * QTOT * CCH;
#pragma unroll
    for (int t = 0; t < 4; ++t) {
#pragma unroll
        for (int cg = 0; cg < 4; ++cg)
#pragma unroll
            for (int j = 0; j < 4; ++j) {
                int q = qbase + t * 16 + 4 * hi + j;
                int c = cg * 16 + r;
                wsv[(size_t)q * CCH + c] = __float2bfloat16(acc[t][cg][j]);
            }
        if (lane < 16)
            ws_w[(size_t)s * QTOT + qbase + t * 16 + lane] = wsum[t];
    }
}

// ---------- reduce + normalize: bf16 partials -> f32 out ----------
__global__ __launch_bounds__(256)
void splat_reduce_bf(const __hip_bfloat16* __restrict__ ws_val,  // [NS][QTOT][64] bf16
                     const float* __restrict__ ws_w,             // [NS][QTOT]
                     float* __restrict__ out, int NS) {
    int t = blockIdx.x * 256 + threadIdx.x;   // t = q*8 + g (8-channel group)
    int q = t >> 3;
    int g = t & 7;
    float a[8];
#pragma unroll
    for (int j = 0; j < 8; ++j) a[j] = 0.0f;
    float wsum = 0.0f;
    for (int s = 0; s < NS; ++s) {
        bf16x8 v = *(const bf16x8*)(ws_val + (size_t)s * QTOT * CCH + (size_t)q * CCH + g * 8);
#pragma unroll
        for (int j = 0; j < 8; ++j) {
            unsigned u = ((unsigned)(unsigned short)v[j]) << 16;
            a[j] += __uint_as_float(u);
        }
        wsum += ws_w[(size_t)s * QTOT + q];
    }
    float inv = 1.0f / (1e-4f + wsum);
    float4 o0 = make_float4(a[0] * inv, a[1] * inv, a[2] * inv, a[3] * inv);
    float4 o1 = make_float4(a[4] * inv, a[5] * inv, a[6] * inv, a[7] * inv);
    float4* op = (float4*)(out + (size_t)q * CCH + g * 8);
    op[0] = o0;
    op[1] = o1;
}

// ---------- fallback: single pass VALU ----------
__global__ __launch_bounds__(256)
void splat_direct(const float* __restrict__ q_pos,
                  const float* __restrict__ d_pos,
                  const float* __restrict__ d_val,
                  float* __restrict__ out, int Q, int N)
{
    const int q = blockIdx.x * blockDim.x + threadIdx.x;
    const float qx = q_pos[q * 3 + 0], qy = q_pos[q * 3 + 1], qz = q_pos[q * 3 + 2];
    float acc[CCH];
#pragma unroll
    for (int c = 0; c < CCH; ++c) acc[c] = 0.0f;
    float wsum = 0.0f;
    for (int n = 0; n < N; ++n) {
        float dx = qx - d_pos[n * 3 + 0];
        float dy = qy - d_pos[n * 3 + 1];
        float dz = qz - d_pos[n * 3 + 2];
        float r2 = fmaf(dx, dx, fmaf(dy, dy, dz * dz));
        float w = __expf(-50.0f * r2);
        wsum += w;
        const float4* row4 = reinterpret_cast<const float4*>(d_val + (size_t)n * CCH);
#pragma unroll
        for (int j = 0; j < CCH / 4; ++j) {
            float4 v = row4[j];
            acc[4 * j + 0] = fmaf(w, v.x, acc[4 * j + 0]);
            acc[4 * j + 1] = fmaf(w, v.y, acc[4 * j + 1]);
            acc[4 * j + 2] = fmaf(w, v.z, acc[4 * j + 2]);
            acc[4 * j + 3] = fmaf(w, v.w, acc[4 * j + 3]);
        }
    }
    float inv = 1.0f / (1e-4f + wsum);
#pragma unroll
    for (int c = 0; c < CCH; ++c) out[(size_t)q * CCH + c] = acc[c] * inv;
}

extern "C" void kernel_launch(void* const* d_in, const int* in_sizes, int n_in,
                              void* d_out, int out_size, void* d_ws, size_t ws_size,
                              hipStream_t stream) {
    const float* q_pos = (const float*)d_in[0];
    const float* d_pos = (const float*)d_in[1];
    const float* d_val = (const float*)d_in[2];
    float* out = (float*)d_out;

    const size_t p4_bytes = (size_t)NTOT * 16;              // 128 KiB
    const size_t vt_bytes = (size_t)NTOT * CCH * 2;         // 1 MiB
    auto need = [&](int ns) {
        return p4_bytes + vt_bytes
             + (size_t)ns * QTOT * CCH * 2   // bf16 partials
             + (size_t)ns * QTOT * 4;        // f32 wsum
    };

    int NS;
    if (need(8) <= ws_size)       NS = 8;    // 512 blocks = 2048 waves = reg-cap fill
    else if (need(4) <= ws_size)  NS = 4;
    else {
        splat_direct<<<dim3(QTOT / 256), dim3(256), 0, stream>>>(
            q_pos, d_pos, d_val, out, QTOT, NTOT);
        return;
    }

    float4*          P4 = (float4*)d_ws;
    __hip_bfloat16*  Vt = (__hip_bfloat16*)((char*)d_ws + p4_bytes);
    __hip_bfloat16* ws_valp = (__hip_bfloat16*)((char*)d_ws + p4_bytes + vt_bytes);
    float*           ws_wp = (float*)((char*)d_ws + p4_bytes + vt_bytes
                                      + (size_t)NS * QTOT * CCH * 2);

    prep_p4<<<dim3(NTOT / 256), dim3(256), 0, stream>>>(d_pos, P4);
    prep_vt<<<dim3(NTOT * CCH / 256), dim3(256), 0, stream>>>(d_val, Vt);

    splat_mfma<<<dim3(QTOT / 256, NS), dim3(256), 0, stream>>>(
        q_pos, P4, Vt, ws_valp, ws_wp, NTOT / NS);

    splat_reduce_bf<<<dim3(QTOT * 8 / 256), dim3(256), 0, stream>>>(
        ws_valp, ws_wp, out, NS);
}

// Round 18
// 66.388 us; speedup vs baseline: 3.6726x; 1.0565x over previous
//
#include <hip/hip_runtime.h>
#include <hip/hip_bf16.h>

// out[q,c] = sum_n exp(-50*r2(q,n)) * d_val[n,c] / (1e-4 + sum_n exp(-50*r2(q,n)))
// Q=16384, N=8192, C=64, f32 in/out.
// MFMA formulation: W (generated bf16) @ V (bf16), f32 accumulate.
// Round 18: R17 verbatim except the two prep kernels are fused into ONE
// dispatch (block-partitioned grid: first 32 blocks -> P4, rest -> Vt).
// Saves one launch boundary (~2us) and overlaps P4 compute with Vt's
// scattered writes. No change to the proven main loop or reduce.

#define QTOT 16384
#define NTOT 8192
#define CCH  64

typedef __attribute__((ext_vector_type(8))) short bf16x8;
typedef __attribute__((ext_vector_type(4))) float f32x4;
typedef __attribute__((ext_vector_type(4))) int   i32x4;

// exp(-50 r^2) = exp2( q . p' + A_q + B_n ), p' = 144.2695*p, B_n = -72.13474*|p|^2
#define K2F 144.269504089f
#define K1F 72.1347520444f

// ---------- fused prep: blocks [0,32) -> P4; blocks [32, 32+2048) -> Vt ----------
__global__ __launch_bounds__(256)
void prep_fused(const float* __restrict__ dp, const float* __restrict__ dv,
                float4* __restrict__ P4, __hip_bfloat16* __restrict__ Vt) {
    if (blockIdx.x < 32) {
        // P4[n] = {K2*px, K2*py, K2*pz, -K1*|p|^2}
        int n = blockIdx.x * 256 + threadIdx.x;
        if (n >= NTOT) return;
        float px = dp[3 * n + 0], py = dp[3 * n + 1], pz = dp[3 * n + 2];
        float4 r;
        r.x = K2F * px; r.y = K2F * py; r.z = K2F * pz;
        r.w = -K1F * (px * px + py * py + pz * pz);
        P4[n] = r;
    } else {
        // Vt[c][n] = bf16(d_val[n][c]); t = c*NTOT + n
        int t = (blockIdx.x - 32) * 256 + threadIdx.x;
        int c = t >> 13;                          // NTOT = 8192
        int n = t & (NTOT - 1);
        Vt[t] = __float2bfloat16(dv[n * CCH + c]);
    }
}

// ---------- main: 4 waves/block; 64 q x 64 c per wave; n-slice in steps of 32 ----------
__global__ __launch_bounds__(256)
void splat_mfma(const float* __restrict__ q_pos,
                const float4* __restrict__ P4,
                const __hip_bfloat16* __restrict__ Vt,   // [64][NTOT]
                __hip_bfloat16* __restrict__ ws_val,     // [NS][QTOT][64] bf16
                float* __restrict__ ws_w,                // [NS][QTOT]
                int npers)                               // n per slice (mult of 32)
{
    const int wave = threadIdx.x >> 6;
    const int lane = threadIdx.x & 63;
    const int r    = lane & 15;     // A row / B col / C col index
    const int hi   = lane >> 4;     // k-group
    const int qbase = blockIdx.x * 256 + wave * 64;
    const int s  = blockIdx.y;
    const int n0 = s * npers;

    float qx[4], qy[4], qz[4], Aq[4];
#pragma unroll
    for (int t = 0; t < 4; ++t) {
        int q = qbase + t * 16 + r;
        float x = q_pos[3 * q + 0], y = q_pos[3 * q + 1], z = q_pos[3 * q + 2];
        qx[t] = x; qy[t] = y; qz[t] = z;
        Aq[t] = -K1F * (x * x + y * y + z * z);
    }

    f32x4 acc[4][4];
#pragma unroll
    for (int t = 0; t < 4; ++t)
#pragma unroll
        for (int cg = 0; cg < 4; ++cg)
            acc[t][cg] = (f32x4)(0.0f);
    float wsum[4] = {0.0f, 0.0f, 0.0f, 0.0f};

    for (int nb = n0; nb < n0 + npers; nb += 32) {
        // P4 for this lane's 8 n values (16 lanes per hi-group share -> broadcast)
        float4 p4[8];
        const float4* pp = P4 + nb + 8 * hi;
#pragma unroll
        for (int b = 0; b < 8; ++b) p4[b] = pp[b];

        // B fragments: lane holds V[nb+8*hi+b][cg*16+r] = Vt[cg*16+r][nb+8*hi+b]
        union BF { i32x4 i; bf16x8 v; } bfr[4];
#pragma unroll
        for (int cg = 0; cg < 4; ++cg) {
            const i32x4* bp = (const i32x4*)(Vt + (size_t)(cg * 16 + r) * NTOT + nb + 8 * hi);
            bfr[cg].i = *bp;
        }

        // A fragments: lane holds W[qbase+t*16+r][k=8*hi+b]
        union AF { unsigned u[4]; bf16x8 v; } af[4];
#pragma unroll
        for (int t = 0; t < 4; ++t) {
            float w[8];
#pragma unroll
            for (int b = 0; b < 8; ++b) {
                float bias = p4[b].w + Aq[t];
                float arg = fmaf(qz[t], p4[b].z, fmaf(qy[t], p4[b].y, fmaf(qx[t], p4[b].x, bias)));
                w[b] = __builtin_amdgcn_exp2f(arg);
                wsum[t] += w[b];
            }
#pragma unroll
            for (int d = 0; d < 4; ++d) {
                unsigned u;
                asm("v_cvt_pk_bf16_f32 %0, %1, %2" : "=v"(u) : "v"(w[2 * d]), "v"(w[2 * d + 1]));
                af[t].u[d] = u;
            }
        }

#pragma unroll
        for (int t = 0; t < 4; ++t)
#pragma unroll
            for (int cg = 0; cg < 4; ++cg)
                acc[t][cg] = __builtin_amdgcn_mfma_f32_16x16x32_bf16(af[t].v, bfr[cg].v, acc[t][cg], 0, 0, 0);
    }

    // wsum: lanes with same r hold disjoint n-subsets of the same q -> reduce over hi
#pragma unroll
    for (int t = 0; t < 4; ++t) {
        float wv = wsum[t];
        wv += __shfl_xor(wv, 16);
        wv += __shfl_xor(wv, 32);
        wsum[t] = wv;
    }

    // C layout: col = lane&15 (channel), row = 4*hi + j (q offset); bf16 stores
    __hip_bfloat16* wsv = ws_val + (size_t)s * QTOT * CCH;
#pragma unroll
    for (int t = 0; t < 4; ++t) {
#pragma unroll
        for (int cg = 0; cg < 4; ++cg)
#pragma unroll
            for (int j = 0; j < 4; ++j) {
                int q = qbase + t * 16 + 4 * hi + j;
                int c = cg * 16 + r;
                wsv[(size_t)q * CCH + c] = __float2bfloat16(acc[t][cg][j]);
            }
        if (lane < 16)
            ws_w[(size_t)s * QTOT + qbase + t * 16 + lane] = wsum[t];
    }
}

// ---------- reduce + normalize: bf16 partials -> f32 out ----------
__global__ __launch_bounds__(256)
void splat_reduce_bf(const __hip_bfloat16* __restrict__ ws_val,  // [NS][QTOT][64] bf16
                     const float* __restrict__ ws_w,             // [NS][QTOT]
                     float* __restrict__ out, int NS) {
    int t = blockIdx.x * 256 + threadIdx.x;   // t = q*8 + g (8-channel group)
    int q = t >> 3;
    int g = t & 7;
    float a[8];
#pragma unroll
    for (int j = 0; j < 8; ++j) a[j] = 0.0f;
    float wsum = 0.0f;
    for (int s = 0; s < NS; ++s) {
        bf16x8 v = *(const bf16x8*)(ws_val + (size_t)s * QTOT * CCH + (size_t)q * CCH + g * 8);
#pragma unroll
        for (int j = 0; j < 8; ++j) {
            unsigned u = ((unsigned)(unsigned short)v[j]) << 16;
            a[j] += __uint_as_float(u);
        }
        wsum += ws_w[(size_t)s * QTOT + q];
    }
    float inv = 1.0f / (1e-4f + wsum);
    float4 o0 = make_float4(a[0] * inv, a[1] * inv, a[2] * inv, a[3] * inv);
    float4 o1 = make_float4(a[4] * inv, a[5] * inv, a[6] * inv, a[7] * inv);
    float4* op = (float4*)(out + (size_t)q * CCH + g * 8);
    op[0] = o0;
    op[1] = o1;
}

// ---------- fallback: single pass VALU ----------
__global__ __launch_bounds__(256)
void splat_direct(const float* __restrict__ q_pos,
                  const float* __restrict__ d_pos,
                  const float* __restrict__ d_val,
                  float* __restrict__ out, int Q, int N)
{
    const int q = blockIdx.x * blockDim.x + threadIdx.x;
    const float qx = q_pos[q * 3 + 0], qy = q_pos[q * 3 + 1], qz = q_pos[q * 3 + 2];
    float acc[CCH];
#pragma unroll
    for (int c = 0; c < CCH; ++c) acc[c] = 0.0f;
    float wsum = 0.0f;
    for (int n = 0; n < N; ++n) {
        float dx = qx - d_pos[n * 3 + 0];
        float dy = qy - d_pos[n * 3 + 1];
        float dz = qz - d_pos[n * 3 + 2];
        float r2 = fmaf(dx, dx, fmaf(dy, dy, dz * dz));
        float w = __expf(-50.0f * r2);
        wsum += w;
        const float4* row4 = reinterpret_cast<const float4*>(d_val + (size_t)n * CCH);
#pragma unroll
        for (int j = 0; j < CCH / 4; ++j) {
            float4 v = row4[j];
            acc[4 * j + 0] = fmaf(w, v.x, acc[4 * j + 0]);
            acc[4 * j + 1] = fmaf(w, v.y, acc[4 * j + 1]);
            acc[4 * j + 2] = fmaf(w, v.z, acc[4 * j + 2]);
            acc[4 * j + 3] = fmaf(w, v.w, acc[4 * j + 3]);
        }
    }
    float inv = 1.0f / (1e-4f + wsum);
#pragma unroll
    for (int c = 0; c < CCH; ++c) out[(size_t)q * CCH + c] = acc[c] * inv;
}

extern "C" void kernel_launch(void* const* d_in, const int* in_sizes, int n_in,
                              void* d_out, int out_size, void* d_ws, size_t ws_size,
                              hipStream_t stream) {
    const float* q_pos = (const float*)d_in[0];
    const float* d_pos = (const float*)d_in[1];
    const float* d_val = (const float*)d_in[2];
    float* out = (float*)d_out;

    const size_t p4_bytes = (size_t)NTOT * 16;              // 128 KiB
    const size_t vt_bytes = (size_t)NTOT * CCH * 2;         // 1 MiB
    auto need = [&](int ns) {
        return p4_bytes + vt_bytes
             + (size_t)ns * QTOT * CCH * 2   // bf16 partials
             + (size_t)ns * QTOT * 4;        // f32 wsum
    };

    int NS;
    if (need(8) <= ws_size)       NS = 8;    // 512 blocks = 2048 waves = reg-cap fill
    else if (need(4) <= ws_size)  NS = 4;
    else {
        splat_direct<<<dim3(QTOT / 256), dim3(256), 0, stream>>>(
            q_pos, d_pos, d_val, out, QTOT, NTOT);
        return;
    }

    float4*          P4 = (float4*)d_ws;
    __hip_bfloat16*  Vt = (__hip_bfloat16*)((char*)d_ws + p4_bytes);
    __hip_bfloat16* ws_valp = (__hip_bfloat16*)((char*)d_ws + p4_bytes + vt_bytes);
    float*           ws_wp = (float*)((char*)d_ws + p4_bytes + vt_bytes
                                      + (size_t)NS * QTOT * CCH * 2);

    // fused prep: 32 blocks for P4 + NTOT*CCH/256 = 2048 blocks for Vt
    prep_fused<<<dim3(32 + NTOT * CCH / 256), dim3(256), 0, stream>>>(
        d_pos, d_val, P4, Vt);

    splat_mfma<<<dim3(QTOT / 256, NS), dim3(256), 0, stream>>>(
        q_pos, P4, Vt, ws_valp, ws_wp, NTOT / NS);

    splat_reduce_bf<<<dim3(QTOT * 8 / 256), dim3(256), 0, stream>>>(
        ws_valp, ws_wp, out, NS);
}

// Round 19
// 66.051 us; speedup vs baseline: 3.6914x; 1.0051x over previous
//
#include <hip/hip_runtime.h>
#include <hip/hip_bf16.h>

// out[q,c] = sum_n exp(-50*r2(q,n)) * d_val[n,c] / (1e-4 + sum_n exp(-50*r2(q,n)))
// Q=16384, N=8192, C=64, f32 in/out.
// MFMA formulation: W (generated bf16) @ V (bf16), f32 accumulate.
// Round 19: R18 verbatim + T5 s_setprio(1)/(0) around the MFMA cluster.
// Waves in this kernel free-run (no barriers) at different phases -> the
// attn-style setprio regime (m191 +4-7%), not the lockstep-GEMM null (m190).
// Additive, register-free, no memory-schedule change (R3/5/6/7/13 lesson).

#define QTOT 16384
#define NTOT 8192
#define CCH  64

typedef __attribute__((ext_vector_type(8))) short bf16x8;
typedef __attribute__((ext_vector_type(4))) float f32x4;
typedef __attribute__((ext_vector_type(4))) int   i32x4;

// exp(-50 r^2) = exp2( q . p' + A_q + B_n ), p' = 144.2695*p, B_n = -72.13474*|p|^2
#define K2F 144.269504089f
#define K1F 72.1347520444f

// ---------- fused prep: blocks [0,32) -> P4; blocks [32, 32+2048) -> Vt ----------
__global__ __launch_bounds__(256)
void prep_fused(const float* __restrict__ dp, const float* __restrict__ dv,
                float4* __restrict__ P4, __hip_bfloat16* __restrict__ Vt) {
    if (blockIdx.x < 32) {
        int n = blockIdx.x * 256 + threadIdx.x;
        if (n >= NTOT) return;
        float px = dp[3 * n + 0], py = dp[3 * n + 1], pz = dp[3 * n + 2];
        float4 r;
        r.x = K2F * px; r.y = K2F * py; r.z = K2F * pz;
        r.w = -K1F * (px * px + py * py + pz * pz);
        P4[n] = r;
    } else {
        int t = (blockIdx.x - 32) * 256 + threadIdx.x;
        int c = t >> 13;                          // NTOT = 8192
        int n = t & (NTOT - 1);
        Vt[t] = __float2bfloat16(dv[n * CCH + c]);
    }
}

// ---------- main: 4 waves/block; 64 q x 64 c per wave; n-slice in steps of 32 ----------
__global__ __launch_bounds__(256)
void splat_mfma(const float* __restrict__ q_pos,
                const float4* __restrict__ P4,
                const __hip_bfloat16* __restrict__ Vt,   // [64][NTOT]
                __hip_bfloat16* __restrict__ ws_val,     // [NS][QTOT][64] bf16
                float* __restrict__ ws_w,                // [NS][QTOT]
                int npers)                               // n per slice (mult of 32)
{
    const int wave = threadIdx.x >> 6;
    const int lane = threadIdx.x & 63;
    const int r    = lane & 15;     // A row / B col / C col index
    const int hi   = lane >> 4;     // k-group
    const int qbase = blockIdx.x * 256 + wave * 64;
    const int s  = blockIdx.y;
    const int n0 = s * npers;

    float qx[4], qy[4], qz[4], Aq[4];
#pragma unroll
    for (int t = 0; t < 4; ++t) {
        int q = qbase + t * 16 + r;
        float x = q_pos[3 * q + 0], y = q_pos[3 * q + 1], z = q_pos[3 * q + 2];
        qx[t] = x; qy[t] = y; qz[t] = z;
        Aq[t] = -K1F * (x * x + y * y + z * z);
    }

    f32x4 acc[4][4];
#pragma unroll
    for (int t = 0; t < 4; ++t)
#pragma unroll
        for (int cg = 0; cg < 4; ++cg)
            acc[t][cg] = (f32x4)(0.0f);
    float wsum[4] = {0.0f, 0.0f, 0.0f, 0.0f};

    for (int nb = n0; nb < n0 + npers; nb += 32) {
        // P4 for this lane's 8 n values (16 lanes per hi-group share -> broadcast)
        float4 p4[8];
        const float4* pp = P4 + nb + 8 * hi;
#pragma unroll
        for (int b = 0; b < 8; ++b) p4[b] = pp[b];

        // B fragments: lane holds V[nb+8*hi+b][cg*16+r] = Vt[cg*16+r][nb+8*hi+b]
        union BF { i32x4 i; bf16x8 v; } bfr[4];
#pragma unroll
        for (int cg = 0; cg < 4; ++cg) {
            const i32x4* bp = (const i32x4*)(Vt + (size_t)(cg * 16 + r) * NTOT + nb + 8 * hi);
            bfr[cg].i = *bp;
        }

        // A fragments: lane holds W[qbase+t*16+r][k=8*hi+b]
        union AF { unsigned u[4]; bf16x8 v; } af[4];
#pragma unroll
        for (int t = 0; t < 4; ++t) {
            float w[8];
#pragma unroll
            for (int b = 0; b < 8; ++b) {
                float bias = p4[b].w + Aq[t];
                float arg = fmaf(qz[t], p4[b].z, fmaf(qy[t], p4[b].y, fmaf(qx[t], p4[b].x, bias)));
                w[b] = __builtin_amdgcn_exp2f(arg);
                wsum[t] += w[b];
            }
#pragma unroll
            for (int d = 0; d < 4; ++d) {
                unsigned u;
                asm("v_cvt_pk_bf16_f32 %0, %1, %2" : "=v"(u) : "v"(w[2 * d]), "v"(w[2 * d + 1]));
                af[t].u[d] = u;
            }
        }

        __builtin_amdgcn_s_setprio(1);
#pragma unroll
        for (int t = 0; t < 4; ++t)
#pragma unroll
            for (int cg = 0; cg < 4; ++cg)
                acc[t][cg] = __builtin_amdgcn_mfma_f32_16x16x32_bf16(af[t].v, bfr[cg].v, acc[t][cg], 0, 0, 0);
        __builtin_amdgcn_s_setprio(0);
    }

    // wsum: lanes with same r hold disjoint n-subsets of the same q -> reduce over hi
#pragma unroll
    for (int t = 0; t < 4; ++t) {
        float wv = wsum[t];
        wv += __shfl_xor(wv, 16);
        wv += __shfl_xor(wv, 32);
        wsum[t] = wv;
    }

    // C layout: col = lane&15 (channel), row = 4*hi + j (q offset); bf16 stores
    __hip_bfloat16* wsv = ws_val + (size_t)s * QTOT * CCH;
#pragma unroll
    for (int t = 0; t < 4; ++t) {
#pragma unroll
        for (int cg = 0; cg < 4; ++cg)
#pragma unroll
            for (int j = 0; j < 4; ++j) {
                int q = qbase + t * 16 + 4 * hi + j;
                int c = cg * 16 + r;
                wsv[(size_t)q * CCH + c] = __float2bfloat16(acc[t][cg][j]);
            }
        if (lane < 16)
            ws_w[(size_t)s * QTOT + qbase + t * 16 + lane] = wsum[t];
    }
}

// ---------- reduce + normalize: bf16 partials -> f32 out ----------
__global__ __launch_bounds__(256)
void splat_reduce_bf(const __hip_bfloat16* __restrict__ ws_val,  // [NS][QTOT][64] bf16
                     const float* __restrict__ ws_w,             // [NS][QTOT]
                     float* __restrict__ out, int NS) {
    int t = blockIdx.x * 256 + threadIdx.x;   // t = q*8 + g (8-channel group)
    int q = t >> 3;
    int g = t & 7;
    float a[8];
#pragma unroll
    for (int j = 0; j < 8; ++j) a[j] = 0.0f;
    float wsum = 0.0f;
    for (int s = 0; s < NS; ++s) {
        bf16x8 v = *(const bf16x8*)(ws_val + (size_t)s * QTOT * CCH + (size_t)q * CCH + g * 8);
#pragma unroll
        for (int j = 0; j < 8; ++j) {
            unsigned u = ((unsigned)(unsigned short)v[j]) << 16;
            a[j] += __uint_as_float(u);
        }
        wsum += ws_w[(size_t)s * QTOT + q];
    }
    float inv = 1.0f / (1e-4f + wsum);
    float4 o0 = make_float4(a[0] * inv, a[1] * inv, a[2] * inv, a[3] * inv);
    float4 o1 = make_float4(a[4] * inv, a[5] * inv, a[6] * inv, a[7] * inv);
    float4* op = (float4*)(out + (size_t)q * CCH + g * 8);
    op[0] = o0;
    op[1] = o1;
}

// ---------- fallback: single pass VALU ----------
__global__ __launch_bounds__(256)
void splat_direct(const float* __restrict__ q_pos,
                  const float* __restrict__ d_pos,
                  const float* __restrict__ d_val,
                  float* __restrict__ out, int Q, int N)
{
    const int q = blockIdx.x * blockDim.x + threadIdx.x;
    const float qx = q_pos[q * 3 + 0], qy = q_pos[q * 3 + 1], qz = q_pos[q * 3 + 2];
    float acc[CCH];
#pragma unroll
    for (int c = 0; c < CCH; ++c) acc[c] = 0.0f;
    float wsum = 0.0f;
    for (int n = 0; n < N; ++n) {
        float dx = qx - d_pos[n * 3 + 0];
        float dy = qy - d_pos[n * 3 + 1];
        float dz = qz - d_pos[n * 3 + 2];
        float r2 = fmaf(dx, dx, fmaf(dy, dy, dz * dz));
        float w = __expf(-50.0f * r2);
        wsum += w;
        const float4* row4 = reinterpret_cast<const float4*>(d_val + (size_t)n * CCH);
#pragma unroll
        for (int j = 0; j < CCH / 4; ++j) {
            float4 v = row4[j];
            acc[4 * j + 0] = fmaf(w, v.x, acc[4 * j + 0]);
            acc[4 * j + 1] = fmaf(w, v.y, acc[4 * j + 1]);
            acc[4 * j + 2] = fmaf(w, v.z, acc[4 * j + 2]);
            acc[4 * j + 3] = fmaf(w, v.w, acc[4 * j + 3]);
        }
    }
    float inv = 1.0f / (1e-4f + wsum);
#pragma unroll
    for (int c = 0; c < CCH; ++c) out[(size_t)q * CCH + c] = acc[c] * inv;
}

extern "C" void kernel_launch(void* const* d_in, const int* in_sizes, int n_in,
                              void* d_out, int out_size, void* d_ws, size_t ws_size,
                              hipStream_t stream) {
    const float* q_pos = (const float*)d_in[0];
    const float* d_pos = (const float*)d_in[1];
    const float* d_val = (const float*)d_in[2];
    float* out = (float*)d_out;

    const size_t p4_bytes = (size_t)NTOT * 16;              // 128 KiB
    const size_t vt_bytes = (size_t)NTOT * CCH * 2;         // 1 MiB
    auto need = [&](int ns) {
        return p4_bytes + vt_bytes
             + (size_t)ns * QTOT * CCH * 2   // bf16 partials
             + (size_t)ns * QTOT * 4;        // f32 wsum
    };

    int NS;
    if (need(8) <= ws_size)       NS = 8;    // 512 blocks = 2048 waves = reg-cap fill
    else if (need(4) <= ws_size)  NS = 4;
    else {
        splat_direct<<<dim3(QTOT / 256), dim3(256), 0, stream>>>(
            q_pos, d_pos, d_val, out, QTOT, NTOT);
        return;
    }

    float4*          P4 = (float4*)d_ws;
    __hip_bfloat16*  Vt = (__hip_bfloat16*)((char*)d_ws + p4_bytes);
    __hip_bfloat16* ws_valp = (__hip_bfloat16*)((char*)d_ws + p4_bytes + vt_bytes);
    float*           ws_wp = (float*)((char*)d_ws + p4_bytes + vt_bytes
                                      + (size_t)NS * QTOT * CCH * 2);

    prep_fused<<<dim3(32 + NTOT * CCH / 256), dim3(256), 0, stream>>>(
        d_pos, d_val, P4, Vt);

    splat_mfma<<<dim3(QTOT / 256, NS), dim3(256), 0, stream>>>(
        q_pos, P4, Vt, ws_valp, ws_wp, NTOT / NS);

    splat_reduce_bf<<<dim3(QTOT * 8 / 256), dim3(256), 0, stream>>>(
        ws_valp, ws_wp, out, NS);
}